// Round 1
// baseline (145.219 us; speedup 1.0000x reference)
//
#include <hip/hip_runtime.h>

#define ALPHA 0.2f
#define LOG2E 1.44269504088896340736f

constexpr int BB  = 4;
constexpr int NN  = 2048;
constexpr int FIN = 128;
constexpr int FO  = 64;
constexpr int HH  = 4;
constexpr int CC  = BB * HH;   // 16 (b,h) combos

using half8   = __attribute__((ext_vector_type(8))) _Float16;
using floatx4 = __attribute__((ext_vector_type(4))) float;

__device__ __forceinline__ void fma4(float4& A, float xs, const float4& Wv) {
  A.x = fmaf(xs, Wv.x, A.x);
  A.y = fmaf(xs, Wv.y, A.y);
  A.z = fmaf(xs, Wv.z, A.z);
  A.w = fmaf(xs, Wv.w, A.w);
}

__device__ __forceinline__ float fast_exp2(float x) {
#if __has_builtin(__builtin_amdgcn_exp2f)
  return __builtin_amdgcn_exp2f(x);
#else
  return exp2f(x);
#endif
}

// ---------------------------------------------------------------------------
// K1: projection ht = h·W  (fp32 vector FMA, register-blocked 8n x 4o per
// thread), esrc/edst fused (stored pre-scaled by log2e so K3 can use raw
// v_exp_f32), htT written f16 transposed [c][f][n] via LDS transpose.
// grid 256 blocks x 256 thr; wave = head.
// ---------------------------------------------------------------------------
__global__ __launch_bounds__(256) void gat_k1_prep(
    const float* __restrict__ h, const float* __restrict__ W,
    const float* __restrict__ a, _Float16* __restrict__ htT,
    float* __restrict__ esrc, float* __restrict__ edst) {
  const int blk = blockIdx.x;
  const int b = blk >> 6;
  const int n0 = (blk & 63) * 32;
  const int t = threadIdx.x;
  const int hh = t >> 6;         // head = wave
  const int lane = t & 63;
  const int ng = lane >> 4;      // nodes ng + 4j  (stride-4: bank spread)
  const int og = lane & 15;      // out cols og*4 .. +4

  __shared__ __align__(16) float X[32 * 136];   // 17408 B, stride 136 floats
  __shared__ __align__(16) char  WBuf[32768];   // W k-chunk / htl transpose
  float* Wc = (float*)WBuf;
  _Float16* htl = (_Float16*)WBuf;

  // stage X[32][128] (row stride 136)
  {
    const float4* src = (const float4*)(h + (size_t)(b * NN + n0) * FIN);
#pragma unroll
    for (int i = 0; i < 4; ++i) {
      const int idx = t + i * 256;
      const int row = idx >> 5, c4 = idx & 31;
      *(float4*)&X[row * 136 + c4 * 4] = src[row * 32 + c4];
    }
  }

  float4 acc[8];
#pragma unroll
  for (int j = 0; j < 8; ++j) acc[j] = float4{0.f, 0.f, 0.f, 0.f};

  for (int kc = 0; kc < 4; ++kc) {
    __syncthreads();
    {  // stage Wc = W[:, kc*32:(kc+1)*32, :]  as [4][32][64] f32
      const float4* Wg = (const float4*)W;
      float4* Wc4 = (float4*)Wc;
#pragma unroll
      for (int r = 0; r < 8; ++r) {
        const int idx = t + r * 256;            // 0..2047 float4s
        const int wh = idx >> 9, rest = idx & 511;
        Wc4[idx] = Wg[wh * 2048 + kc * 512 + rest];
      }
    }
    __syncthreads();
    const float4* Wc4 = (const float4*)Wc;
#pragma unroll
    for (int k4 = 0; k4 < 8; ++k4) {
      const float4 w0 = Wc4[hh * 512 + (k4 * 4 + 0) * 16 + og];
      const float4 w1 = Wc4[hh * 512 + (k4 * 4 + 1) * 16 + og];
      const float4 w2 = Wc4[hh * 512 + (k4 * 4 + 2) * 16 + og];
      const float4 w3 = Wc4[hh * 512 + (k4 * 4 + 3) * 16 + og];
#pragma unroll
      for (int j = 0; j < 8; ++j) {
        const float4 x = *(const float4*)&X[(ng + 4 * j) * 136 + kc * 32 + k4 * 4];
        fma4(acc[j], x.x, w0);
        fma4(acc[j], x.y, w1);
        fma4(acc[j], x.z, w2);
        fma4(acc[j], x.w, w3);
      }
    }
  }

  // esrc/edst: partial dot over this thread's 4 cols, reduce over 16 og lanes
  const float4 as4 = *(const float4*)&a[hh * 128 + og * 4];
  const float4 ad4 = *(const float4*)&a[hh * 128 + 64 + og * 4];
  const int c = b * HH + hh;
#pragma unroll
  for (int j = 0; j < 8; ++j) {
    float es = acc[j].x * as4.x + acc[j].y * as4.y + acc[j].z * as4.z + acc[j].w * as4.w;
    float ed = acc[j].x * ad4.x + acc[j].y * ad4.y + acc[j].z * ad4.z + acc[j].w * ad4.w;
#pragma unroll
    for (int off = 1; off < 16; off <<= 1) {
      es += __shfl_xor(es, off, 64);
      ed += __shfl_xor(ed, off, 64);
    }
    if (og == 0) {
      // log2-domain prescale: lrelu is positively homogeneous, so K2's
      // masked-max + lrelu pipeline stays valid on scaled values and K3
      // can use raw v_exp_f32 (exp2) with no per-element multiply.
      esrc[c * NN + n0 + ng + 4 * j] = es * LOG2E;
      edst[c * NN + n0 + ng + 4 * j] = ed * LOG2E;
    }
  }

  __syncthreads();   // Wc reads done; reuse WBuf as htl [4][64][40] f16
#pragma unroll
  for (int j = 0; j < 8; ++j) {
    const int n = ng + 4 * j;
    htl[(hh * 64 + og * 4 + 0) * 40 + n] = (_Float16)acc[j].x;
    htl[(hh * 64 + og * 4 + 1) * 40 + n] = (_Float16)acc[j].y;
    htl[(hh * 64 + og * 4 + 2) * 40 + n] = (_Float16)acc[j].z;
    htl[(hh * 64 + og * 4 + 3) * 40 + n] = (_Float16)acc[j].w;
  }
  __syncthreads();
  {  // coalesced-ish writeout: thread t owns (head t>>6, f t&63), 32 n (64 B)
    const int h2 = t >> 6, f2 = t & 63;
    const uint4* srcl = (const uint4*)&htl[(h2 * 64 + f2) * 40];
    uint4* dst = (uint4*)(htT + (((size_t)(b * HH + h2) * 64 + f2) * NN + n0));
#pragma unroll
    for (int r = 0; r < 4; ++r) dst[r] = srcl[r];
  }
}

// ---------------------------------------------------------------------------
// K2: adjacency bitpack + rmax[c][m] = lrelu(esrc + masked-max(edst)).
// NO exp (lrelu monotone => max commutes). Operates transparently on
// log2e-scaled esrc/edst (lrelu homogeneous). grid 512 x 256; wave per row.
// ---------------------------------------------------------------------------
__global__ __launch_bounds__(256) void gat_k2_stats(
    const float* __restrict__ adj, const float* __restrict__ esrc,
    const float* __restrict__ edst, unsigned* __restrict__ adjbits,
    float* __restrict__ rmax) {
  const int t = threadIdx.x;
  const int w = t >> 6, l = t & 63;
  const int m = blockIdx.x * 4 + w;

  float areg[32];
  const float* arow = adj + (size_t)m * NN;
#pragma unroll
  for (int j = 0; j < 32; ++j) areg[j] = arow[j * 64 + l];

#pragma unroll
  for (int j = 0; j < 32; ++j) {
    const unsigned long long mask = __ballot(areg[j] != 0.f);
    if (l == 0) {
      adjbits[m * 64 + j * 2 + 0] = (unsigned)mask;
      adjbits[m * 64 + j * 2 + 1] = (unsigned)(mask >> 32);
    }
  }

  for (int cc = 0; cc < CC; ++cc) {
    float mx = -3.0e38f;
#pragma unroll
    for (int j = 0; j < 32; ++j) {
      float ed = edst[cc * NN + j * 64 + l];
      ed = (areg[j] != 0.f) ? ed : -3.0e38f;
      mx = fmaxf(mx, ed);
    }
#pragma unroll
    for (int off = 32; off > 0; off >>= 1) mx = fmaxf(mx, __shfl_xor(mx, off, 64));
    if (l == 0) {
      const float s = esrc[cc * NN + m] + mx;
      rmax[cc * NN + m] = (s >= 0.f) ? s : ALPHA * s;
    }
  }
}

// ---------------------------------------------------------------------------
// K3: O = softmax(P)·V, P built on the fly DIRECTLY in A-fragment registers
// (no LDS P). All e-values are in log2 domain -> raw v_exp_f32 per element.
// V double-buffered via async global_load_lds with XOR swizzle.
// Unnormalized accumulate + psum; epilogue divides. grid 512 x 256.
// ---------------------------------------------------------------------------
__global__ __launch_bounds__(256) void gat_k3_pv(
    const _Float16* __restrict__ htT, const float* __restrict__ esrc,
    const float* __restrict__ edst, const unsigned* __restrict__ adjbits,
    const float* __restrict__ rmax, float* __restrict__ out) {
  const int blk = blockIdx.x;
  const int c = blk >> 5;
  const int m0 = (blk & 31) * 64;
  const int b = c >> 2, hh = c & 3;
  const int t = threadIdx.x;
  const int w = t >> 6, lane = t & 63;
  const int q = lane >> 4, r16 = lane & 15;
  const int row = m0 + w * 16 + r16;   // this thread's A-fragment row

  __shared__ __align__(16) _Float16 Vt[2 * 64 * 64];  // 2 x 8 KB, swizzled
  __shared__ float rowsum[64];

  const float em = esrc[c * NN + row];
  const float rm = rmax[c * NN + row];
  const float* edc = edst + (size_t)c * NN;
  const unsigned* abrow = adjbits + (size_t)row * 64;
  const _Float16* vsrc = htT + (size_t)c * FO * NN;

  // stage thread->chunk mapping: chunk idx = t (and t+256); row fr, slot sg.
  // XOR swizzle: LDS slot sg of row fr holds global chunk sg^(fr&7).
  const int fr0 = t >> 3, sg0 = t & 7;
  const int fr1 = (t + 256) >> 3;
  const size_t goff0 = (size_t)fr0 * NN + (size_t)((sg0 ^ (fr0 & 7)) * 8);
  const size_t goff1 = (size_t)fr1 * NN + (size_t)((sg0 ^ (fr1 & 7)) * 8);

  floatx4 acc[4];
#pragma unroll
  for (int ft = 0; ft < 4; ++ft) acc[ft] = floatx4{0.f, 0.f, 0.f, 0.f};
  float psum = 0.f;

#define STAGE(BUF, NBASE)                                                      \
  do {                                                                         \
    __builtin_amdgcn_global_load_lds(                                          \
        (const __attribute__((address_space(1))) void*)(vsrc + goff0 + (NBASE)),\
        (__attribute__((address_space(3))) void*)((char*)Vt + (BUF)*8192 + t*16),\
        16, 0, 0);                                                             \
    __builtin_amdgcn_global_load_lds(                                          \
        (const __attribute__((address_space(1))) void*)(vsrc + goff1 + (NBASE)),\
        (__attribute__((address_space(3))) void*)((char*)Vt + (BUF)*8192 + (t+256)*16),\
        16, 0, 0);                                                             \
  } while (0)

  STAGE(0, 0);

  for (int it = 0; it < 32; ++it) {
    const int n0 = it * 64;
    // ---- build A-fragments (this row, k = q*8..+8 within each 32-window)
    half8 afrag[2];
    const uint2 bw = *(const uint2*)&abrow[n0 >> 5];
    const float4* edp = (const float4*)(edc + n0);
#pragma unroll
    for (int kk2 = 0; kk2 < 2; ++kk2) {
      const float4 ea = edp[kk2 * 8 + q * 2];
      const float4 eb = edp[kk2 * 8 + q * 2 + 1];
      const float xs[8] = {ea.x, ea.y, ea.z, ea.w, eb.x, eb.y, eb.z, eb.w};
      const unsigned bits = ((kk2 == 0) ? bw.x : bw.y) >> (q * 8);
#pragma unroll
      for (int k = 0; k < 8; ++k) {
        float s = em + xs[k];
        s = (s >= 0.f) ? s : ALPHA * s;
        float p = fast_exp2(s - rm);
        p = ((bits >> k) & 1u) ? p : 0.f;
        psum += p;
        afrag[kk2][k] = (_Float16)p;
      }
    }
    // barrier (drains vmcnt: current buffer's DMA complete everywhere)
    __syncthreads();
    if (it + 1 < 32) STAGE((it + 1) & 1, n0 + 64);
    // ---- MFMA from swizzled LDS V tile
    const int bufo = (it & 1) * 4096;  // halves
#pragma unroll
    for (int kk2 = 0; kk2 < 2; ++kk2) {
#pragma unroll
      for (int ft = 0; ft < 4; ++ft) {
        const int fr = ft * 16 + r16;
        const int cq = kk2 * 4 + q;
        const half8 bfrag =
            *(const half8*)&Vt[bufo + fr * 64 + ((cq ^ (fr & 7)) * 8)];
        acc[ft] = __builtin_amdgcn_mfma_f32_16x16x32_f16(afrag[kk2], bfrag,
                                                         acc[ft], 0, 0, 0);
      }
    }
  }

  // ---- row sums: reduce over the 4 q-lanes sharing this row
  psum += __shfl_xor(psum, 16, 64);
  psum += __shfl_xor(psum, 32, 64);
  if (q == 0) rowsum[w * 16 + r16] = psum;
  __syncthreads();

  // ---- epilogue: C layout col=lane&15, row=q*4+reg; normalize
#pragma unroll
  for (int x = 0; x < 4; ++x) {
    const float rinv = 1.0f / rowsum[w * 16 + q * 4 + x];
    const int mrow = m0 + w * 16 + q * 4 + x;
    float* op = out + ((size_t)b * NN + mrow) * 256 + hh * 64;
#pragma unroll
    for (int ft = 0; ft < 4; ++ft) op[ft * 16 + r16] = acc[ft][x] * rinv;
  }
#undef STAGE
}

// ---------------------------------------------------------------------------
extern "C" void kernel_launch(void* const* d_in, const int* in_sizes, int n_in,
                              void* d_out, int out_size, void* d_ws, size_t ws_size,
                              hipStream_t stream) {
  const float* h   = (const float*)d_in[0];   // (4,2048,128)
  const float* adj = (const float*)d_in[1];   // (2048,2048)
  const float* W   = (const float*)d_in[2];   // (4,128,64)
  const float* a   = (const float*)d_in[3];   // (4,128,1)
  float* out = (float*)d_out;                  // (4,2048,256)

  char* ws = (char*)d_ws;
  _Float16* htT   = (_Float16*)(ws);                         // 4 MB
  float* esrc     = (float*)(ws + 4 * 1024 * 1024);           // 128 KB
  float* edst     = (float*)(ws + 4 * 1024 * 1024 + 131072);  // 128 KB
  unsigned* abits = (unsigned*)(ws + 4 * 1024 * 1024 + 2 * 131072);        // 512 KB
  float* rmax     = (float*)(ws + 4 * 1024 * 1024 + 2 * 131072 + 524288);  // 128 KB

  gat_k1_prep<<<dim3(BB * (NN / 32)), dim3(256), 0, stream>>>(h, W, a, htT, esrc, edst);
  gat_k2_stats<<<dim3(NN / 4), dim3(256), 0, stream>>>(adj, esrc, edst, abits, rmax);
  gat_k3_pv<<<dim3(CC * (NN / 64)), dim3(256), 0, stream>>>(htT, esrc, edst, abits, rmax, out);
}

// Round 2
// 137.273 us; speedup vs baseline: 1.0579x; 1.0579x over previous
//
#include <hip/hip_runtime.h>

#define ALPHA 0.2f
#define LOG2E 1.44269504088896340736f

constexpr int BB  = 4;
constexpr int NN  = 2048;
constexpr int FIN = 128;
constexpr int FO  = 64;
constexpr int HH  = 4;
constexpr int CC  = BB * HH;   // 16 (b,h) combos

using half8   = __attribute__((ext_vector_type(8))) _Float16;
using floatx4 = __attribute__((ext_vector_type(4))) float;

__device__ __forceinline__ void fma4(float4& A, float xs, const float4& Wv) {
  A.x = fmaf(xs, Wv.x, A.x);
  A.y = fmaf(xs, Wv.y, A.y);
  A.z = fmaf(xs, Wv.z, A.z);
  A.w = fmaf(xs, Wv.w, A.w);
}

__device__ __forceinline__ float fast_exp2(float x) {
#if __has_builtin(__builtin_amdgcn_exp2f)
  return __builtin_amdgcn_exp2f(x);
#else
  return exp2f(x);
#endif
}

// ---------------------------------------------------------------------------
// K1: projection ht = h·W (fp32 vector FMA, register-blocked 4n x 4o per
// thread), esrc/edst fused (stored pre-scaled by log2e so K3 can use raw
// v_exp_f32), htT written f16 transposed [c][f][n] via LDS transpose.
// Tile = 16 nodes -> grid 512 (2 blocks/CU, was 1) for latency hiding.
// ---------------------------------------------------------------------------
__global__ __launch_bounds__(256) void gat_k1_prep(
    const float* __restrict__ h, const float* __restrict__ W,
    const float* __restrict__ a, _Float16* __restrict__ htT,
    float* __restrict__ esrc, float* __restrict__ edst) {
  const int blk = blockIdx.x;
  const int b = blk >> 7;
  const int n0 = (blk & 127) * 16;
  const int t = threadIdx.x;
  const int hh = t >> 6;         // head = wave
  const int lane = t & 63;
  const int ng = lane >> 4;      // nodes ng + 4j (stride-4: bank spread)
  const int og = lane & 15;      // out cols og*4 .. +4

  __shared__ __align__(16) float X[16 * 136];   // row stride 136 floats
  __shared__ __align__(16) char  WBuf[32768];   // W k-chunk / htl transpose
  float* Wc = (float*)WBuf;
  _Float16* htl = (_Float16*)WBuf;

  // stage X[16][128] (row stride 136)
  {
    const float4* src = (const float4*)(h + (size_t)(b * NN + n0) * FIN);
#pragma unroll
    for (int i = 0; i < 2; ++i) {
      const int idx = t + i * 256;
      const int row = idx >> 5, c4 = idx & 31;
      *(float4*)&X[row * 136 + c4 * 4] = src[row * 32 + c4];
    }
  }

  float4 acc[4];
#pragma unroll
  for (int j = 0; j < 4; ++j) acc[j] = float4{0.f, 0.f, 0.f, 0.f};

  for (int kc = 0; kc < 4; ++kc) {
    __syncthreads();
    {  // stage Wc = W[:, kc*32:(kc+1)*32, :] as [4][32][64] f32
      const float4* Wg = (const float4*)W;
      float4* Wc4 = (float4*)Wc;
#pragma unroll
      for (int r = 0; r < 8; ++r) {
        const int idx = t + r * 256;            // 0..2047 float4s
        const int wh = idx >> 9, rest = idx & 511;
        Wc4[idx] = Wg[wh * 2048 + kc * 512 + rest];
      }
    }
    __syncthreads();
    const float4* Wc4 = (const float4*)Wc;
#pragma unroll
    for (int k4 = 0; k4 < 8; ++k4) {
      const float4 w0 = Wc4[hh * 512 + (k4 * 4 + 0) * 16 + og];
      const float4 w1 = Wc4[hh * 512 + (k4 * 4 + 1) * 16 + og];
      const float4 w2 = Wc4[hh * 512 + (k4 * 4 + 2) * 16 + og];
      const float4 w3 = Wc4[hh * 512 + (k4 * 4 + 3) * 16 + og];
#pragma unroll
      for (int j = 0; j < 4; ++j) {
        const float4 x = *(const float4*)&X[(ng + 4 * j) * 136 + kc * 32 + k4 * 4];
        fma4(acc[j], x.x, w0);
        fma4(acc[j], x.y, w1);
        fma4(acc[j], x.z, w2);
        fma4(acc[j], x.w, w3);
      }
    }
  }

  // esrc/edst: partial dot over this thread's 4 cols, reduce over 16 og lanes
  const float4 as4 = *(const float4*)&a[hh * 128 + og * 4];
  const float4 ad4 = *(const float4*)&a[hh * 128 + 64 + og * 4];
  const int c = b * HH + hh;
#pragma unroll
  for (int j = 0; j < 4; ++j) {
    float es = acc[j].x * as4.x + acc[j].y * as4.y + acc[j].z * as4.z + acc[j].w * as4.w;
    float ed = acc[j].x * ad4.x + acc[j].y * ad4.y + acc[j].z * ad4.z + acc[j].w * ad4.w;
#pragma unroll
    for (int off = 1; off < 16; off <<= 1) {
      es += __shfl_xor(es, off, 64);
      ed += __shfl_xor(ed, off, 64);
    }
    if (og == 0) {
      // log2-domain prescale: lrelu positively homogeneous, so K2/K3 stay
      // valid on scaled values and K3 uses raw v_exp_f32 (exp2).
      esrc[c * NN + n0 + ng + 4 * j] = es * LOG2E;
      edst[c * NN + n0 + ng + 4 * j] = ed * LOG2E;
    }
  }

  __syncthreads();   // Wc reads done; reuse WBuf as htl [4][64][..] stride 40
#pragma unroll
  for (int j = 0; j < 4; ++j) {
    const int n = ng + 4 * j;
    htl[(hh * 64 + og * 4 + 0) * 40 + n] = (_Float16)acc[j].x;
    htl[(hh * 64 + og * 4 + 1) * 40 + n] = (_Float16)acc[j].y;
    htl[(hh * 64 + og * 4 + 2) * 40 + n] = (_Float16)acc[j].z;
    htl[(hh * 64 + og * 4 + 3) * 40 + n] = (_Float16)acc[j].w;
  }
  __syncthreads();
  {  // writeout: thread t owns (head t>>6, f t&63), 16 n (32 B)
    const int h2 = t >> 6, f2 = t & 63;
    const uint4* srcl = (const uint4*)&htl[(h2 * 64 + f2) * 40];
    uint4* dst = (uint4*)(htT + (((size_t)(b * HH + h2) * 64 + f2) * NN + n0));
#pragma unroll
    for (int r = 0; r < 2; ++r) dst[r] = srcl[r];
  }
}

// ---------------------------------------------------------------------------
// K2: adjacency bitpack + rmax[c][m] = lrelu(esrc + masked-max(edst)).
// NO exp (lrelu monotone => max commutes). Operates transparently on
// log2e-scaled esrc/edst. grid 512 x 256; wave per row.
// ---------------------------------------------------------------------------
__global__ __launch_bounds__(256) void gat_k2_stats(
    const float* __restrict__ adj, const float* __restrict__ esrc,
    const float* __restrict__ edst, unsigned* __restrict__ adjbits,
    float* __restrict__ rmax) {
  const int t = threadIdx.x;
  const int w = t >> 6, l = t & 63;
  const int m = blockIdx.x * 4 + w;

  float areg[32];
  const float* arow = adj + (size_t)m * NN;
#pragma unroll
  for (int j = 0; j < 32; ++j) areg[j] = arow[j * 64 + l];

#pragma unroll
  for (int j = 0; j < 32; ++j) {
    const unsigned long long mask = __ballot(areg[j] != 0.f);
    if (l == 0) {
      adjbits[m * 64 + j * 2 + 0] = (unsigned)mask;
      adjbits[m * 64 + j * 2 + 1] = (unsigned)(mask >> 32);
    }
  }

  for (int cc = 0; cc < CC; ++cc) {
    float mx = -3.0e38f;
#pragma unroll
    for (int j = 0; j < 32; ++j) {
      float ed = edst[cc * NN + j * 64 + l];
      ed = (areg[j] != 0.f) ? ed : -3.0e38f;
      mx = fmaxf(mx, ed);
    }
#pragma unroll
    for (int off = 32; off > 0; off >>= 1) mx = fmaxf(mx, __shfl_xor(mx, off, 64));
    if (l == 0) {
      const float s = esrc[cc * NN + m] + mx;
      rmax[cc * NN + m] = (s >= 0.f) ? s : ALPHA * s;
    }
  }
}

// ---------------------------------------------------------------------------
// K3: O = softmax(P)·V, P built on the fly DIRECTLY in A-fragment registers.
// NEW: 8 waves/block (512 thr), waves split 2-way over k -> 16 waves/CU.
// V staged [64f][128n] f16 double-buffered (32 KB) via global_load_lds with
// XOR swizzle. Row sums via ones-MFMA (no per-element psum). lrelu-max fold
// absorbs the -rm subtraction. Cross-group reduce through LDS at end.
// grid 512 x 512.
// ---------------------------------------------------------------------------
__global__ __launch_bounds__(512) void gat_k3_pv(
    const _Float16* __restrict__ htT, const float* __restrict__ esrc,
    const float* __restrict__ edst, const unsigned* __restrict__ adjbits,
    const float* __restrict__ rmax, float* __restrict__ out) {
  const int blk = blockIdx.x;
  const int c = blk >> 5;
  const int m0 = (blk & 31) * 64;
  const int b = c >> 2, hh = c & 3;
  const int t = threadIdx.x;
  const int w = t >> 6;          // 0..7
  const int kg = w >> 2;         // k-group: waves 0-3 vs 4-7
  const int wl = w & 3;          // row-group within 64-row tile
  const int lane = t & 63;
  const int q = lane >> 4, r16 = lane & 15;
  const int row = m0 + wl * 16 + r16;   // this thread's A-fragment row

  __shared__ __align__(16) _Float16 Vt[2 * 64 * 128];  // 2 x 16 KB, swizzled

  const float em = esrc[c * NN + row];
  const float rm = rmax[c * NN + row];
  const float em1 = em - rm;                 // for max(em1+x, ...)
  const float em2 = fmaf(ALPHA, em, -rm);    // 0.2*em - rm
  const float* edc = edst + (size_t)c * NN;
  const unsigned* abrow = adjbits + (size_t)row * 64;
  const _Float16* vsrc = htT + (size_t)c * FO * NN;

  // staging: 1024 chunks of 16B per buffer ([64f][128n] f16). chunk idx ->
  // f = idx>>4, slot = idx&15; LDS linear dest, global src pre-swizzled:
  // slot sg of row f holds global n-octet sg^(f&15).
  const int f0 = t >> 4, sg0 = t & 15;
  const int f1 = (t + 512) >> 4;
  const size_t goff0 = (size_t)f0 * NN + (size_t)((sg0 ^ (f0 & 15)) * 8);
  const size_t goff1 = (size_t)f1 * NN + (size_t)((sg0 ^ (f1 & 15)) * 8);

  floatx4 acc[4];
#pragma unroll
  for (int ft = 0; ft < 4; ++ft) acc[ft] = floatx4{0.f, 0.f, 0.f, 0.f};
  floatx4 accs = floatx4{0.f, 0.f, 0.f, 0.f};

  half8 ones;
#pragma unroll
  for (int k = 0; k < 8; ++k) ones[k] = (_Float16)1.0f;

#define STAGE(BUF, NBASE)                                                      \
  do {                                                                         \
    __builtin_amdgcn_global_load_lds(                                          \
        (const __attribute__((address_space(1))) void*)(vsrc + goff0 + (NBASE)),\
        (__attribute__((address_space(3))) void*)((char*)Vt + (BUF)*16384 + t*16),\
        16, 0, 0);                                                             \
    __builtin_amdgcn_global_load_lds(                                          \
        (const __attribute__((address_space(1))) void*)(vsrc + goff1 + (NBASE)),\
        (__attribute__((address_space(3))) void*)((char*)Vt + (BUF)*16384 + (t+512)*16),\
        16, 0, 0);                                                             \
  } while (0)

  STAGE(0, 0);

  for (int step = 0; step < 16; ++step) {
    const int n0k = step * 128 + kg * 64;   // this group's 64-wide k-window
    // ---- build A-fragments (this row, k = q*8..+8 within each 32-window)
    half8 afrag[2];
    const uint2 bw = *(const uint2*)&abrow[n0k >> 5];
    const float4* edp = (const float4*)(edc + n0k);
#pragma unroll
    for (int kk2 = 0; kk2 < 2; ++kk2) {
      const float4 ea = edp[kk2 * 8 + q * 2];
      const float4 eb = edp[kk2 * 8 + q * 2 + 1];
      const float xs[8] = {ea.x, ea.y, ea.z, ea.w, eb.x, eb.y, eb.z, eb.w};
      const unsigned bits = ((kk2 == 0) ? bw.x : bw.y) >> (q * 8);
#pragma unroll
      for (int k = 0; k < 8; ++k) {
        const float t1 = em1 + xs[k];
        const float t2 = fmaf(ALPHA, xs[k], em2);
        float p = fast_exp2(fmaxf(t1, t2));   // = exp2(lrelu(em+x) - rm)
        p = ((bits >> k) & 1u) ? p : 0.f;
        afrag[kk2][k] = (_Float16)p;
      }
    }
    // barrier (drains vmcnt: current buffer's DMA complete everywhere)
    __syncthreads();
    if (step + 1 < 16) STAGE((step + 1) & 1, (step + 1) * 128);
    // ---- MFMA from swizzled LDS V tile (+ ones-MFMA row sums)
    const int bufo = (step & 1) * 8192;  // halves
#pragma unroll
    for (int kk2 = 0; kk2 < 2; ++kk2) {
      accs = __builtin_amdgcn_mfma_f32_16x16x32_f16(afrag[kk2], ones, accs, 0, 0, 0);
#pragma unroll
      for (int ft = 0; ft < 4; ++ft) {
        const int fr = ft * 16 + r16;
        const int octet = kg * 8 + kk2 * 4 + q;
        const half8 bfrag =
            *(const half8*)&Vt[bufo + fr * 128 + ((octet ^ (fr & 15)) * 8)];
        acc[ft] = __builtin_amdgcn_mfma_f32_16x16x32_f16(afrag[kk2], bfrag,
                                                         acc[ft], 0, 0, 0);
      }
    }
  }

  // ---- cross-group reduction through LDS (reuse Vt; 21504 B < 32768 B)
  __syncthreads();
  float* abuf = (float*)Vt;
  if (kg == 1) {
    const int tl = t - 256;   // 0..255
#pragma unroll
    for (int ft = 0; ft < 4; ++ft)
#pragma unroll
      for (int x = 0; x < 4; ++x) abuf[tl * 21 + ft * 4 + x] = acc[ft][x];
#pragma unroll
    for (int x = 0; x < 4; ++x) abuf[tl * 21 + 16 + x] = accs[x];
  }
  __syncthreads();
  if (kg == 0) {
#pragma unroll
    for (int ft = 0; ft < 4; ++ft)
#pragma unroll
      for (int x = 0; x < 4; ++x) acc[ft][x] += abuf[t * 21 + ft * 4 + x];
#pragma unroll
    for (int x = 0; x < 4; ++x) accs[x] += abuf[t * 21 + 16 + x];

    // ---- epilogue: C layout col=lane&15, row=q*4+reg; accs[x] = row sum
#pragma unroll
    for (int x = 0; x < 4; ++x) {
      const float rinv = 1.0f / accs[x];
      const int mrow = m0 + wl * 16 + q * 4 + x;
      float* op = out + ((size_t)b * NN + mrow) * 256 + hh * 64;
#pragma unroll
      for (int ft = 0; ft < 4; ++ft) op[ft * 16 + r16] = acc[ft][x] * rinv;
    }
  }
#undef STAGE
}

// ---------------------------------------------------------------------------
extern "C" void kernel_launch(void* const* d_in, const int* in_sizes, int n_in,
                              void* d_out, int out_size, void* d_ws, size_t ws_size,
                              hipStream_t stream) {
  const float* h   = (const float*)d_in[0];   // (4,2048,128)
  const float* adj = (const float*)d_in[1];   // (2048,2048)
  const float* W   = (const float*)d_in[2];   // (4,128,64)
  const float* a   = (const float*)d_in[3];   // (4,128,1)
  float* out = (float*)d_out;                  // (4,2048,256)

  char* ws = (char*)d_ws;
  _Float16* htT   = (_Float16*)(ws);                         // 4 MB
  float* esrc     = (float*)(ws + 4 * 1024 * 1024);           // 128 KB
  float* edst     = (float*)(ws + 4 * 1024 * 1024 + 131072);  // 128 KB
  unsigned* abits = (unsigned*)(ws + 4 * 1024 * 1024 + 2 * 131072);        // 512 KB
  float* rmax     = (float*)(ws + 4 * 1024 * 1024 + 2 * 131072 + 524288);  // 128 KB

  gat_k1_prep<<<dim3(BB * (NN / 16)), dim3(256), 0, stream>>>(h, W, a, htT, esrc, edst);
  gat_k2_stats<<<dim3(NN / 4), dim3(256), 0, stream>>>(adj, esrc, edst, abits, rmax);
  gat_k3_pv<<<dim3(CC * (NN / 64)), dim3(512), 0, stream>>>(htT, esrc, edst, abits, rmax, out);
}

// Round 3
// 128.387 us; speedup vs baseline: 1.1311x; 1.0692x over previous
//
#include <hip/hip_runtime.h>

#define ALPHA 0.2f
#define LOG2E 1.44269504088896340736f

constexpr int BB  = 4;
constexpr int NN  = 2048;
constexpr int FIN = 128;
constexpr int FO  = 64;
constexpr int HH  = 4;
constexpr int CC  = BB * HH;   // 16 (b,h) combos

using half8   = __attribute__((ext_vector_type(8))) _Float16;
using floatx4 = __attribute__((ext_vector_type(4))) float;

__device__ __forceinline__ float fast_exp2(float x) {
#if __has_builtin(__builtin_amdgcn_exp2f)
  return __builtin_amdgcn_exp2f(x);
#else
  return exp2f(x);
#endif
}

union PK4 { _Float16 f[4]; uint2 u; };

// ---------------------------------------------------------------------------
// K1: ht = h·W via f16 MFMA (fp32 accum). e via associativity:
// esrc = h·(W·a_src) computed in FP32-exact during staging (log2e-scaled).
// Block = one (b,head) x 64 nodes; 4 waves each own 16 rows x 64 f.
// A = h[n][k] (LDS f16, XOR-chunk swizzle), B = WT[f][k] (LDS f16, swizzled).
// grid 512 x 256.
// ---------------------------------------------------------------------------
__global__ __launch_bounds__(256) void gat_k1_prep(
    const float* __restrict__ h, const float* __restrict__ W,
    const float* __restrict__ a, _Float16* __restrict__ htT,
    float* __restrict__ esrcT, float* __restrict__ edst) {
  const int blk = blockIdx.x;
  const int c  = blk >> 5;           // 0..15
  const int n0 = (blk & 31) * 64;
  const int b = c >> 2, hh = c & 3;
  const int t = threadIdx.x;
  const int w = t >> 6, lane = t & 63;
  const int q = lane >> 4, r16 = lane & 15;

  __shared__ __align__(16) _Float16 Xs[64 * 128];   // 16 KB swizzled h-tile
  __shared__ __align__(16) _Float16 WT[64 * 128];   // 16 KB swizzled W^T
  __shared__ float wasb[128];
  __shared__ float wadb[128];

  // --- was/wad: (W·a_src)[k], (W·a_dst)[k]  (fp32, 128 threads each) ---
  {
    const int k = t & 127;
    const float* wrow = W + ((size_t)hh * 128 + k) * 64;
    const float* av = a + hh * 128 + ((t >> 7) << 6);
    float s = 0.f;
#pragma unroll
    for (int o = 0; o < 16; ++o) {
      const float4 wv = *(const float4*)(wrow + o * 4);
      const float4 av4 = *(const float4*)(av + o * 4);
      s += wv.x * av4.x + wv.y * av4.y + wv.z * av4.z + wv.w * av4.w;
    }
    if (t < 128) wasb[k] = s; else wadb[k] = s;
  }

  // --- stage WT[f][k] f16, 16B-chunk XOR swizzle: slot = (k>>3) ^ (f&15) ---
  {
    const int k = t >> 1, fh = (t & 1) * 32;
    const float* wsrc = W + ((size_t)hh * 128 + k) * 64 + fh;
    const int chunk = k >> 3, within = k & 7;
#pragma unroll
    for (int i = 0; i < 8; ++i) {
      const float4 v = *(const float4*)(wsrc + i * 4);
      const _Float16 f4[4] = {(_Float16)v.x, (_Float16)v.y,
                              (_Float16)v.z, (_Float16)v.w};
#pragma unroll
      for (int u = 0; u < 4; ++u) {
        const int f = fh + i * 4 + u;
        WT[f * 128 + ((chunk ^ (f & 15)) << 3) + within] = f4[u];
      }
    }
  }

  __syncthreads();   // wasb/wadb ready

  // --- stage Xs[n][k] f16 (swizzled) + fp32 e-partials ---
  {
    const int r = t >> 2, cq = t & 3;   // row r (0..63), col-quarter cq*32
    const float* hsrc = h + ((size_t)(b * NN + n0 + r)) * FIN + cq * 32;
    float es = 0.f, ed = 0.f;
#pragma unroll
    for (int i = 0; i < 8; ++i) {
      const float4 v = *(const float4*)(hsrc + i * 4);
      const float4 ws = *(const float4*)&wasb[cq * 32 + i * 4];
      const float4 wd = *(const float4*)&wadb[cq * 32 + i * 4];
      es += v.x * ws.x + v.y * ws.y + v.z * ws.z + v.w * ws.w;
      ed += v.x * wd.x + v.y * wd.y + v.z * wd.z + v.w * wd.w;
      PK4 pk;
      pk.f[0] = (_Float16)v.x; pk.f[1] = (_Float16)v.y;
      pk.f[2] = (_Float16)v.z; pk.f[3] = (_Float16)v.w;
      const int chunk = cq * 4 + (i >> 1);
      *(uint2*)&Xs[r * 128 + ((chunk ^ (r & 15)) << 3) + (i & 1) * 4] = pk.u;
    }
    es += __shfl_xor(es, 1, 64); es += __shfl_xor(es, 2, 64);
    ed += __shfl_xor(ed, 1, 64); ed += __shfl_xor(ed, 2, 64);
    if (cq == 0) {
      esrcT[(size_t)(n0 + r) * CC + c] = es * LOG2E;
      edst[(size_t)c * NN + n0 + r]    = ed * LOG2E;
    }
  }

  __syncthreads();

  // --- MFMA: wave w owns rows n0 + w*16 + [0,16), all 64 f ---
  floatx4 acc[4];
#pragma unroll
  for (int ft = 0; ft < 4; ++ft) acc[ft] = floatx4{0.f, 0.f, 0.f, 0.f};

  half8 afrag[4];
#pragma unroll
  for (int ks = 0; ks < 4; ++ks) {
    const int slot = (ks * 4 + q) ^ r16;
    afrag[ks] = *(const half8*)&Xs[(w * 16 + r16) * 128 + (slot << 3)];
  }
#pragma unroll
  for (int ks = 0; ks < 4; ++ks) {
#pragma unroll
    for (int ft = 0; ft < 4; ++ft) {
      const int fr = ft * 16 + r16;
      const int slot = (ks * 4 + q) ^ (fr & 15);
      const half8 bfrag = *(const half8*)&WT[fr * 128 + (slot << 3)];
      acc[ft] = __builtin_amdgcn_mfma_f32_16x16x32_f16(afrag[ks], bfrag,
                                                       acc[ft], 0, 0, 0);
    }
  }

  // --- epilogue: C col=lane&15 (=f within tile), row=q*4+reg (=n) ---
#pragma unroll
  for (int ft = 0; ft < 4; ++ft) {
    PK4 pk;
#pragma unroll
    for (int x = 0; x < 4; ++x) pk.f[x] = (_Float16)acc[ft][x];
    const int fcol = ft * 16 + r16;
    const int n = n0 + w * 16 + q * 4;
    *(uint2*)(htT + ((size_t)c * FO + fcol) * NN + n) = pk.u;
  }
}

// ---------------------------------------------------------------------------
// K2: adjacency bitpack + rmaxT[m][c] = lrelu(esrc + masked-max(edst)).
// edst staged per-block in LDS 512-col chunks [16c][520n] (shared by 4 row-
// waves => 4x less L2 traffic). grid 512 x 256.
// ---------------------------------------------------------------------------
__global__ __launch_bounds__(256) void gat_k2_stats(
    const float* __restrict__ adj, const float* __restrict__ esrcT,
    const float* __restrict__ edst, unsigned* __restrict__ adjbits,
    float* __restrict__ rmaxT) {
  const int t = threadIdx.x;
  const int w = t >> 6, l = t & 63;
  const int m = blockIdx.x * 4 + w;

  __shared__ float eds[16 * 520];   // 33.3 KB

  float areg[32];
  const float* arow = adj + (size_t)m * NN;
#pragma unroll
  for (int j = 0; j < 32; ++j) areg[j] = arow[j * 64 + l];

#pragma unroll
  for (int j = 0; j < 32; ++j) {
    const unsigned long long mask = __ballot(areg[j] != 0.f);
    if (l == 0) {
      adjbits[m * 64 + j * 2 + 0] = (unsigned)mask;
      adjbits[m * 64 + j * 2 + 1] = (unsigned)(mask >> 32);
    }
  }

  float4 mv[4];
#pragma unroll
  for (int i = 0; i < 4; ++i) mv[i] = float4{-3.0e38f, -3.0e38f, -3.0e38f, -3.0e38f};

  for (int ch = 0; ch < 4; ++ch) {
    __syncthreads();
    {  // stage edst[:, ch*512 .. +512]
#pragma unroll
      for (int i = 0; i < 8; ++i) {
        const int idx = t + i * 256;          // 0..2047 float4
        const int cc = idx >> 7, nf = idx & 127;
        const float4 v =
            *(const float4*)(edst + (size_t)cc * NN + ch * 512 + nf * 4);
        *(float4*)&eds[cc * 520 + nf * 4] = v;
      }
    }
    __syncthreads();
#pragma unroll
    for (int j2 = 0; j2 < 8; ++j2) {
      const bool on = (areg[ch * 8 + j2] != 0.f);
      const int nl = j2 * 64 + l;
#pragma unroll
      for (int i = 0; i < 4; ++i) {
        float4 e4;
        e4.x = eds[(i * 4 + 0) * 520 + nl];
        e4.y = eds[(i * 4 + 1) * 520 + nl];
        e4.z = eds[(i * 4 + 2) * 520 + nl];
        e4.w = eds[(i * 4 + 3) * 520 + nl];
        mv[i].x = fmaxf(mv[i].x, on ? e4.x : -3.0e38f);
        mv[i].y = fmaxf(mv[i].y, on ? e4.y : -3.0e38f);
        mv[i].z = fmaxf(mv[i].z, on ? e4.z : -3.0e38f);
        mv[i].w = fmaxf(mv[i].w, on ? e4.w : -3.0e38f);
      }
    }
  }

#pragma unroll
  for (int off = 1; off < 64; off <<= 1) {
#pragma unroll
    for (int i = 0; i < 4; ++i) {
      mv[i].x = fmaxf(mv[i].x, __shfl_xor(mv[i].x, off, 64));
      mv[i].y = fmaxf(mv[i].y, __shfl_xor(mv[i].y, off, 64));
      mv[i].z = fmaxf(mv[i].z, __shfl_xor(mv[i].z, off, 64));
      mv[i].w = fmaxf(mv[i].w, __shfl_xor(mv[i].w, off, 64));
    }
  }
  if (l == 0) {
#pragma unroll
    for (int i = 0; i < 4; ++i) {
      const float4 es = *(const float4*)&esrcT[(size_t)m * CC + i * 4];
      float4 o;
      const float sx = es.x + mv[i].x; o.x = (sx >= 0.f) ? sx : ALPHA * sx;
      const float sy = es.y + mv[i].y; o.y = (sy >= 0.f) ? sy : ALPHA * sy;
      const float sz = es.z + mv[i].z; o.z = (sz >= 0.f) ? sz : ALPHA * sz;
      const float sw = es.w + mv[i].w; o.w = (sw >= 0.f) ? sw : ALPHA * sw;
      *(float4*)&rmaxT[(size_t)m * CC + i * 4] = o;
    }
  }
}

// ---------------------------------------------------------------------------
// K3: O = softmax(P)·V, P built in A-fragment registers. 1024 thr = 16 waves:
// 4 row-groups x 4 k-groups -> 32 waves/CU (100% cap). V double-buffered via
// global_load_lds + XOR swizzle. Row sums via ones-MFMA. Mask folded before
// exp2 (tt = bit ? tt : -3e38 -> p = 0 exact). 3-partial LDS reduce at end.
// grid 512 x 1024.
// ---------------------------------------------------------------------------
__global__ __launch_bounds__(1024) void gat_k3_pv(
    const _Float16* __restrict__ htT, const float* __restrict__ esrcT,
    const float* __restrict__ edst, const unsigned* __restrict__ adjbits,
    const float* __restrict__ rmaxT, float* __restrict__ out) {
  const int blk = blockIdx.x;
  const int c = blk >> 5;
  const int m0 = (blk & 31) * 64;
  const int b = c >> 2, hh = c & 3;
  const int t = threadIdx.x;
  const int w = t >> 6;        // 0..15
  const int kg = w >> 2;       // k-group 0..3 (32-wide k-window each)
  const int wl = w & 3;        // row-group
  const int lane = t & 63;
  const int q = lane >> 4, r16 = lane & 15;
  const int row = m0 + wl * 16 + r16;

  // LDS: staging 2x16KB (Vt) overlapped later by 3x256x21 f32 reduce buffer
  __shared__ __align__(16) char smem[64512];
  _Float16* Vt = (_Float16*)smem;
  float* abuf = (float*)smem;

  const float em = esrcT[(size_t)row * CC + c];
  const float rm = rmaxT[(size_t)row * CC + c];
  const float em1 = em - rm;
  const float em2 = fmaf(ALPHA, em, -rm);
  const float* edc = edst + (size_t)c * NN;
  const unsigned* abrow = adjbits + (size_t)row * 64;
  const _Float16* vsrc = htT + (size_t)c * FO * NN;

  // staging map: chunk t -> f = t>>4, slot sg = t&15; linear LDS dest,
  // pre-swizzled global src: slot sg of row f holds global n-octet sg^(f&15)
  const int f0 = t >> 4, sg0 = t & 15;
  const size_t goff0 = (size_t)f0 * NN + (size_t)((sg0 ^ (f0 & 15)) * 8);

  floatx4 acc[4];
#pragma unroll
  for (int ft = 0; ft < 4; ++ft) acc[ft] = floatx4{0.f, 0.f, 0.f, 0.f};
  floatx4 accs = floatx4{0.f, 0.f, 0.f, 0.f};

  half8 ones;
#pragma unroll
  for (int k = 0; k < 8; ++k) ones[k] = (_Float16)1.0f;

#define STAGE(BUF, NBASE)                                                      \
  __builtin_amdgcn_global_load_lds(                                            \
      (const __attribute__((address_space(1))) void*)(vsrc + goff0 + (NBASE)), \
      (__attribute__((address_space(3))) void*)(smem + (BUF)*16384 + t*16),    \
      16, 0, 0)

  STAGE(0, 0);

  for (int step = 0; step < 16; ++step) {
    const int n0k = step * 128 + kg * 32;   // this k-group's 32-wide window
    // ---- build A-fragment (this row, k = q*8..+8 within the 32-window)
    half8 afrag;
    const unsigned bits = abrow[step * 4 + kg] >> (q * 8);
    const float4 ea = *(const float4*)(edc + n0k + q * 8);
    const float4 eb = *(const float4*)(edc + n0k + q * 8 + 4);
    const float xs[8] = {ea.x, ea.y, ea.z, ea.w, eb.x, eb.y, eb.z, eb.w};
#pragma unroll
    for (int k = 0; k < 8; ++k) {
      const float t1 = em1 + xs[k];
      const float t2 = fmaf(ALPHA, xs[k], em2);
      float tt = fmaxf(t1, t2);                 // lrelu(em+x) - rm  (log2 dom)
      tt = ((bits >> k) & 1u) ? tt : -3.0e38f;  // masked -> exp2 -> exact 0
      afrag[k] = (_Float16)fast_exp2(tt);
    }
    // barrier drains vmcnt: current buffer's DMA complete everywhere
    __syncthreads();
    if (step + 1 < 16) STAGE((step + 1) & 1, (step + 1) * 128);
    // ---- MFMA from swizzled LDS V tile (+ ones-MFMA row sums)
    const int bufo = (step & 1) * 8192;  // f16 elements
    accs = __builtin_amdgcn_mfma_f32_16x16x32_f16(afrag, ones, accs, 0, 0, 0);
#pragma unroll
    for (int ft = 0; ft < 4; ++ft) {
      const int fr = ft * 16 + r16;
      const int oct = kg * 4 + q;
      const half8 bfrag =
          *(const half8*)&Vt[bufo + fr * 128 + ((oct ^ (fr & 15)) << 3)];
      acc[ft] = __builtin_amdgcn_mfma_f32_16x16x32_f16(afrag, bfrag,
                                                       acc[ft], 0, 0, 0);
    }
  }

  // ---- 4-way k-group reduction through LDS (single shot, stride 21)
  __syncthreads();
  if (kg >= 1) {
    const int base = ((kg - 1) * 256 + (t & 255)) * 21;
#pragma unroll
    for (int ft = 0; ft < 4; ++ft)
#pragma unroll
      for (int x = 0; x < 4; ++x) abuf[base + ft * 4 + x] = acc[ft][x];
#pragma unroll
    for (int x = 0; x < 4; ++x) abuf[base + 16 + x] = accs[x];
  }
  __syncthreads();
  if (kg == 0) {
#pragma unroll
    for (int g = 0; g < 3; ++g) {
      const int base = (g * 256 + t) * 21;
#pragma unroll
      for (int ft = 0; ft < 4; ++ft)
#pragma unroll
        for (int x = 0; x < 4; ++x) acc[ft][x] += abuf[base + ft * 4 + x];
#pragma unroll
      for (int x = 0; x < 4; ++x) accs[x] += abuf[base + 16 + x];
    }
    // ---- epilogue: C layout col=lane&15, row=q*4+reg; accs[x] = row sum
#pragma unroll
    for (int x = 0; x < 4; ++x) {
      const float rinv = 1.0f / accs[x];
      const int mrow = m0 + wl * 16 + q * 4 + x;
      float* op = out + ((size_t)b * NN + mrow) * 256 + hh * 64;
#pragma unroll
      for (int ft = 0; ft < 4; ++ft) op[ft * 16 + r16] = acc[ft][x] * rinv;
    }
  }
#undef STAGE
}

// ---------------------------------------------------------------------------
extern "C" void kernel_launch(void* const* d_in, const int* in_sizes, int n_in,
                              void* d_out, int out_size, void* d_ws, size_t ws_size,
                              hipStream_t stream) {
  const float* h   = (const float*)d_in[0];   // (4,2048,128)
  const float* adj = (const float*)d_in[1];   // (2048,2048)
  const float* W   = (const float*)d_in[2];   // (4,128,64)
  const float* a   = (const float*)d_in[3];   // (4,128,1)
  float* out = (float*)d_out;                  // (4,2048,256)

  char* ws = (char*)d_ws;
  _Float16* htT   = (_Float16*)(ws);                         // 4 MB
  float* esrcT    = (float*)(ws + 4 * 1024 * 1024);           // 128 KB [n][c]
  float* edst     = (float*)(ws + 4 * 1024 * 1024 + 131072);  // 128 KB [c][n]
  unsigned* abits = (unsigned*)(ws + 4 * 1024 * 1024 + 2 * 131072);        // 512 KB
  float* rmaxT    = (float*)(ws + 4 * 1024 * 1024 + 2 * 131072 + 524288);  // 128 KB [m][c]

  gat_k1_prep<<<dim3(CC * (NN / 64)), dim3(256), 0, stream>>>(h, W, a, htT, esrcT, edst);
  gat_k2_stats<<<dim3(NN / 4), dim3(256), 0, stream>>>(adj, esrcT, edst, abits, rmaxT);
  gat_k3_pv<<<dim3(CC * (NN / 64)), dim3(1024), 0, stream>>>(htT, esrcT, edst, abits, rmaxT, out);
}

// Round 4
// 112.094 us; speedup vs baseline: 1.2955x; 1.1453x over previous
//
#include <hip/hip_runtime.h>

#define ALPHA 0.2f
#define LOG2E 1.44269504088896340736f

constexpr int BB  = 4;
constexpr int NN  = 2048;
constexpr int FIN = 128;
constexpr int FO  = 64;
constexpr int HH  = 4;
constexpr int CC  = BB * HH;   // 16 (b,h) combos

using half8   = __attribute__((ext_vector_type(8))) _Float16;
using floatx4 = __attribute__((ext_vector_type(4))) float;

__device__ __forceinline__ float fast_exp2(float x) {
#if __has_builtin(__builtin_amdgcn_exp2f)
  return __builtin_amdgcn_exp2f(x);
#else
  return exp2f(x);
#endif
}

union PK4 { _Float16 f[4]; uint2 u; };

// ---------------------------------------------------------------------------
// K12: two block roles in one kernel (independent work, co-scheduled).
//  blocks 0..511   : projection ht = h·W via f16 MFMA (fp32 accum);
//                    esrc/edst via associativity h·(W·a) in fp32-exact
//                    (log2e-scaled); per-(c,tile) edst max -> gpart.
//  blocks 512..1023: adjacency bitpack (wave per row, ballot).
// grid 1024 x 256.
// ---------------------------------------------------------------------------
__global__ __launch_bounds__(256) void gat_k12(
    const float* __restrict__ h, const float* __restrict__ W,
    const float* __restrict__ a, const float* __restrict__ adj,
    _Float16* __restrict__ htT, float* __restrict__ esrcT,
    float* __restrict__ edst, float* __restrict__ gpart,
    unsigned* __restrict__ adjbits) {
  const int blk = blockIdx.x;
  const int t = threadIdx.x;
  const int w = t >> 6, lane = t & 63;

  if (blk >= 512) {
    // ---------------- role 2: adjacency bitpack ----------------
    const int m = (blk - 512) * 4 + w;
    float areg[32];
    const float* arow = adj + (size_t)m * NN;
#pragma unroll
    for (int j = 0; j < 32; ++j) areg[j] = arow[j * 64 + lane];
#pragma unroll
    for (int j = 0; j < 32; ++j) {
      const unsigned long long mask = __ballot(areg[j] != 0.f);
      if (lane == 0) {
        adjbits[m * 64 + j * 2 + 0] = (unsigned)mask;
        adjbits[m * 64 + j * 2 + 1] = (unsigned)(mask >> 32);
      }
    }
    return;
  }

  // ---------------- role 1: projection ----------------
  const int c  = blk >> 5;           // 0..15
  const int nt = blk & 31;
  const int n0 = nt * 64;
  const int b = c >> 2, hh = c & 3;
  const int q = lane >> 4, r16 = lane & 15;

  __shared__ __align__(16) _Float16 Xs[64 * 128];   // 16 KB swizzled h-tile
  __shared__ __align__(16) _Float16 WT[64 * 128];   // 16 KB swizzled W^T
  __shared__ float wasb[128];
  __shared__ float wadb[128];
  __shared__ float edsh[64];

  // --- was/wad: (W·a_src)[k], (W·a_dst)[k]  (fp32, 128 threads each) ---
  {
    const int k = t & 127;
    const float* wrow = W + ((size_t)hh * 128 + k) * 64;
    const float* av = a + hh * 128 + ((t >> 7) << 6);
    float s = 0.f;
#pragma unroll
    for (int o = 0; o < 16; ++o) {
      const float4 wv = *(const float4*)(wrow + o * 4);
      const float4 av4 = *(const float4*)(av + o * 4);
      s += wv.x * av4.x + wv.y * av4.y + wv.z * av4.z + wv.w * av4.w;
    }
    if (t < 128) wasb[k] = s; else wadb[k] = s;
  }

  // --- stage WT[f][k] f16, 16B-chunk XOR swizzle: slot = (k>>3) ^ (f&15) ---
  {
    const int k = t >> 1, fh = (t & 1) * 32;
    const float* wsrc = W + ((size_t)hh * 128 + k) * 64 + fh;
    const int chunk = k >> 3, within = k & 7;
#pragma unroll
    for (int i = 0; i < 8; ++i) {
      const float4 v = *(const float4*)(wsrc + i * 4);
      const _Float16 f4[4] = {(_Float16)v.x, (_Float16)v.y,
                              (_Float16)v.z, (_Float16)v.w};
#pragma unroll
      for (int u = 0; u < 4; ++u) {
        const int f = fh + i * 4 + u;
        WT[f * 128 + ((chunk ^ (f & 15)) << 3) + within] = f4[u];
      }
    }
  }

  __syncthreads();   // wasb/wadb ready (also orders WT writes)

  // --- stage Xs[n][k] f16 (swizzled) + fp32 e-partials ---
  {
    const int r = t >> 2, cq = t & 3;   // row r (0..63), col-quarter cq*32
    const float* hsrc = h + ((size_t)(b * NN + n0 + r)) * FIN + cq * 32;
    float es = 0.f, ed = 0.f;
#pragma unroll
    for (int i = 0; i < 8; ++i) {
      const float4 v = *(const float4*)(hsrc + i * 4);
      const float4 ws = *(const float4*)&wasb[cq * 32 + i * 4];
      const float4 wd = *(const float4*)&wadb[cq * 32 + i * 4];
      es += v.x * ws.x + v.y * ws.y + v.z * ws.z + v.w * ws.w;
      ed += v.x * wd.x + v.y * wd.y + v.z * wd.z + v.w * wd.w;
      PK4 pk;
      pk.f[0] = (_Float16)v.x; pk.f[1] = (_Float16)v.y;
      pk.f[2] = (_Float16)v.z; pk.f[3] = (_Float16)v.w;
      const int chunk = cq * 4 + (i >> 1);
      *(uint2*)&Xs[r * 128 + ((chunk ^ (r & 15)) << 3) + (i & 1) * 4] = pk.u;
    }
    es += __shfl_xor(es, 1, 64); es += __shfl_xor(es, 2, 64);
    ed += __shfl_xor(ed, 1, 64); ed += __shfl_xor(ed, 2, 64);
    if (cq == 0) {
      const float edl = ed * LOG2E;
      esrcT[(size_t)(n0 + r) * CC + c] = es * LOG2E;
      edst[(size_t)c * NN + n0 + r]    = edl;
      edsh[r] = edl;
    }
  }

  __syncthreads();   // Xs + edsh ready

  // --- per-(c,tile) edst max -> gpart (wave 0) ---
  if (t < 64) {
    float v = edsh[t];
#pragma unroll
    for (int off = 1; off < 64; off <<= 1) v = fmaxf(v, __shfl_xor(v, off, 64));
    if (t == 0) gpart[c * 32 + nt] = v;
  }

  // --- MFMA: wave w owns rows n0 + w*16 + [0,16), all 64 f ---
  floatx4 acc[4];
#pragma unroll
  for (int ft = 0; ft < 4; ++ft) acc[ft] = floatx4{0.f, 0.f, 0.f, 0.f};

  half8 afrag[4];
#pragma unroll
  for (int ks = 0; ks < 4; ++ks) {
    const int slot = (ks * 4 + q) ^ r16;
    afrag[ks] = *(const half8*)&Xs[(w * 16 + r16) * 128 + (slot << 3)];
  }
#pragma unroll
  for (int ks = 0; ks < 4; ++ks) {
#pragma unroll
    for (int ft = 0; ft < 4; ++ft) {
      const int fr = ft * 16 + r16;
      const int slot = (ks * 4 + q) ^ (fr & 15);
      const half8 bfrag = *(const half8*)&WT[fr * 128 + (slot << 3)];
      acc[ft] = __builtin_amdgcn_mfma_f32_16x16x32_f16(afrag[ks], bfrag,
                                                       acc[ft], 0, 0, 0);
    }
  }

  // --- epilogue: C col=lane&15 (=f within tile), row=q*4+reg (=n) ---
#pragma unroll
  for (int ft = 0; ft < 4; ++ft) {
    PK4 pk;
#pragma unroll
    for (int x = 0; x < 4; ++x) pk.f[x] = (_Float16)acc[ft][x];
    const int fcol = ft * 16 + r16;
    const int n = n0 + w * 16 + q * 4;
    *(uint2*)(htT + ((size_t)c * FO + fcol) * NN + n) = pk.u;
  }
}

// ---------------------------------------------------------------------------
// K3: O = softmax(P)·V, P built in A-fragment registers. 1024 thr = 16 waves:
// 4 row-groups x 4 k-groups -> 32 waves/CU. V double-buffered via
// global_load_lds + XOR swizzle. edst staged ONCE in LDS (kills 268 MB of
// redundant L2 reads). rm = lrelu(em + gmax_c) computed in prologue (exact
// masked max replaced by per-c upper bound; softmax shift cancels).
// Row sums via ones-MFMA. grid 512 x 1024.
// ---------------------------------------------------------------------------
__global__ __launch_bounds__(1024) void gat_k3_pv(
    const _Float16* __restrict__ htT, const float* __restrict__ esrcT,
    const float* __restrict__ edst, const unsigned* __restrict__ adjbits,
    const float* __restrict__ gpart, float* __restrict__ out) {
  const int blk = blockIdx.x;
  const int c = blk >> 5;
  const int m0 = (blk & 31) * 64;
  const int b = c >> 2, hh = c & 3;
  const int t = threadIdx.x;
  const int w = t >> 6;        // 0..15
  const int kg = w >> 2;       // k-group 0..3 (32-wide k-window each)
  const int wl = w & 3;        // row-group
  const int lane = t & 63;
  const int q = lane >> 4, r16 = lane & 15;
  const int row = m0 + wl * 16 + r16;

  // LDS map: [0,32768) Vt double buffer; [32768,40960) edsF; [40960,40964)
  // gmax; epilogue reduce buffer reuses [0,64512).
  __shared__ __align__(16) char smem[64512];
  _Float16* Vt = (_Float16*)smem;
  float* edsF = (float*)(smem + 32768);
  float* gmaxp = (float*)(smem + 40960);
  float* abuf = (float*)smem;

  const unsigned* abrow = adjbits + (size_t)row * 64;
  const _Float16* vsrc = htT + (size_t)c * FO * NN;

  // staging map: chunk t -> f = t>>4, slot sg = t&15; linear LDS dest,
  // pre-swizzled global src: slot sg of row f holds global n-octet sg^(f&15)
  const int f0 = t >> 4, sg0 = t & 15;
  const size_t goff0 = (size_t)f0 * NN + (size_t)((sg0 ^ (f0 & 15)) * 8);

#define STAGE(BUF, NBASE)                                                      \
  __builtin_amdgcn_global_load_lds(                                            \
      (const __attribute__((address_space(1))) void*)(vsrc + goff0 + (NBASE)), \
      (__attribute__((address_space(3))) void*)(smem + (BUF)*16384 + t*16),    \
      16, 0, 0)

  STAGE(0, 0);

  // prologue: stage edc -> LDS (8 KB), reduce gpart -> gmax
  *(float2*)&edsF[t * 2] = *(const float2*)(edst + (size_t)c * NN + t * 2);
  {
    float gv = (t < 32) ? gpart[c * 32 + t] : -3.0e38f;
    if (t < 64) {
#pragma unroll
      for (int off = 1; off < 32; off <<= 1)
        gv = fmaxf(gv, __shfl_xor(gv, off, 64));
      if (t == 0) *gmaxp = gv;
    }
  }
  __syncthreads();   // edsF + gmax visible (also drains STAGE(0))

  const float em = esrcT[(size_t)row * CC + c];
  const float gm = *gmaxp;
  const float s0 = em + gm;
  const float rm = (s0 >= 0.f) ? s0 : ALPHA * s0;   // upper bound on row max
  const float em1 = em - rm;
  const float em2 = fmaf(ALPHA, em, -rm);

  floatx4 acc[4];
#pragma unroll
  for (int ft = 0; ft < 4; ++ft) acc[ft] = floatx4{0.f, 0.f, 0.f, 0.f};
  floatx4 accs = floatx4{0.f, 0.f, 0.f, 0.f};

  half8 ones;
#pragma unroll
  for (int k = 0; k < 8; ++k) ones[k] = (_Float16)1.0f;

  for (int step = 0; step < 16; ++step) {
    const int n0k = step * 128 + kg * 32;   // this k-group's 32-wide window
    // ---- build A-fragment (this row, k = q*8..+8 within the 32-window)
    half8 afrag;
    const unsigned bits = abrow[step * 4 + kg] >> (q * 8);
    const float4 ea = *(const float4*)&edsF[n0k + q * 8];
    const float4 eb = *(const float4*)&edsF[n0k + q * 8 + 4];
    const float xs[8] = {ea.x, ea.y, ea.z, ea.w, eb.x, eb.y, eb.z, eb.w};
#pragma unroll
    for (int k = 0; k < 8; ++k) {
      const float t1 = em1 + xs[k];
      const float t2 = fmaf(ALPHA, xs[k], em2);
      float tt = fmaxf(t1, t2);                 // lrelu(em+x) - rm  (log2 dom)
      tt = ((bits >> k) & 1u) ? tt : -3.0e38f;  // masked -> exp2 -> exact 0
      afrag[k] = (_Float16)fast_exp2(tt);
    }
    // barrier drains vmcnt: current buffer's DMA complete everywhere
    __syncthreads();
    if (step + 1 < 16) STAGE((step + 1) & 1, (step + 1) * 128);
    // ---- MFMA from swizzled LDS V tile (+ ones-MFMA row sums)
    const int bufo = (step & 1) * 8192;  // f16 elements
    accs = __builtin_amdgcn_mfma_f32_16x16x32_f16(afrag, ones, accs, 0, 0, 0);
#pragma unroll
    for (int ft = 0; ft < 4; ++ft) {
      const int fr = ft * 16 + r16;
      const int oct = kg * 4 + q;
      const half8 bfrag =
          *(const half8*)&Vt[bufo + fr * 128 + ((oct ^ (fr & 15)) << 3)];
      acc[ft] = __builtin_amdgcn_mfma_f32_16x16x32_f16(afrag, bfrag,
                                                       acc[ft], 0, 0, 0);
    }
  }

  // ---- 4-way k-group reduction through LDS (single shot, stride 21)
  __syncthreads();
  if (kg >= 1) {
    const int base = ((kg - 1) * 256 + (t & 255)) * 21;
#pragma unroll
    for (int ft = 0; ft < 4; ++ft)
#pragma unroll
      for (int x = 0; x < 4; ++x) abuf[base + ft * 4 + x] = acc[ft][x];
#pragma unroll
    for (int x = 0; x < 4; ++x) abuf[base + 16 + x] = accs[x];
  }
  __syncthreads();
  if (kg == 0) {
#pragma unroll
    for (int g = 0; g < 3; ++g) {
      const int base = (g * 256 + t) * 21;
#pragma unroll
      for (int ft = 0; ft < 4; ++ft)
#pragma unroll
        for (int x = 0; x < 4; ++x) acc[ft][x] += abuf[base + ft * 4 + x];
#pragma unroll
      for (int x = 0; x < 4; ++x) accs[x] += abuf[base + 16 + x];
    }
    // ---- epilogue: C layout col=lane&15, row=q*4+reg; accs[x] = row sum
#pragma unroll
    for (int x = 0; x < 4; ++x) {
      const float rinv = 1.0f / accs[x];
      const int mrow = m0 + wl * 16 + q * 4 + x;
      float* op = out + ((size_t)b * NN + mrow) * 256 + hh * 64;
#pragma unroll
      for (int ft = 0; ft < 4; ++ft) op[ft * 16 + r16] = acc[ft][x] * rinv;
    }
  }
#undef STAGE
}

// ---------------------------------------------------------------------------
extern "C" void kernel_launch(void* const* d_in, const int* in_sizes, int n_in,
                              void* d_out, int out_size, void* d_ws, size_t ws_size,
                              hipStream_t stream) {
  const float* h   = (const float*)d_in[0];   // (4,2048,128)
  const float* adj = (const float*)d_in[1];   // (2048,2048)
  const float* W   = (const float*)d_in[2];   // (4,128,64)
  const float* a   = (const float*)d_in[3];   // (4,128,1)
  float* out = (float*)d_out;                  // (4,2048,256)

  char* ws = (char*)d_ws;
  _Float16* htT   = (_Float16*)(ws);                         // 4 MB
  float* esrcT    = (float*)(ws + 4 * 1024 * 1024);           // 128 KB [n][c]
  float* edst     = (float*)(ws + 4 * 1024 * 1024 + 131072);  // 128 KB [c][n]
  unsigned* abits = (unsigned*)(ws + 4 * 1024 * 1024 + 2 * 131072);        // 512 KB
  float* gpart    = (float*)(ws + 4 * 1024 * 1024 + 2 * 131072 + 524288);  // 2 KB [c][32]

  gat_k12<<<dim3(1024), dim3(256), 0, stream>>>(h, W, a, adj, htT, esrcT,
                                                edst, gpart, abits);
  gat_k3_pv<<<dim3(CC * (NN / 64)), dim3(1024), 0, stream>>>(htT, esrcT, edst,
                                                             abits, gpart, out);
}